// Round 9
// baseline (39.955 us; speedup 1.0000x reference)
//
#include <hip/hip_runtime.h>

typedef __bf16 bf16x8 __attribute__((ext_vector_type(8)));
typedef float f32x4 __attribute__((ext_vector_type(4)));

__device__ __forceinline__ unsigned short f2bf(float f) {
  __bf16 h = (__bf16)f;
  return __builtin_bit_cast(unsigned short, h);
}

// d_ws layout: [0, 24576) bytes: wsB bf16 fragment-ordered (12288 shorts)
//              [24576, 24832): bias (64 floats)
// wsB flat idx = (((di*4 + jblk)*2 + kstep)*64 + lane)*8 + i
//   c   = kstep*32 + 4*(lane>>4) + (i&3) + 16*(i>>2)
//   fch = jblk*16 + (lane&15)
__global__ __launch_bounds__(256) void prep_kernel(
    const float* __restrict__ conv_w, const float* __restrict__ gamma,
    const float* __restrict__ beta, const float* __restrict__ mean,
    const float* __restrict__ var, unsigned short* __restrict__ wsB,
    float* __restrict__ bias) {
  int idx = blockIdx.x * 256 + threadIdx.x;
  if (idx >= 12288) return;
  int di    = idx >> 12;
  int r     = idx & 4095;
  int jblk  = r >> 10;
  int r2    = r & 1023;
  int kstep = r2 >> 9;
  int r3    = r2 & 511;
  int lane  = r3 >> 3;
  int i     = r3 & 7;
  int c   = kstep * 32 + 4 * (lane >> 4) + (i & 3) + 16 * (i >> 2);
  int fch = jblk * 16 + (lane & 15);
  float s = gamma[fch] * rsqrtf(var[fch] + 1e-3f);
  float v = conv_w[((di * 3 + 0) * 64 + c) * 64 + fch]
          + conv_w[((di * 3 + 1) * 64 + c) * 64 + fch]
          + conv_w[((di * 3 + 2) * 64 + c) * 64 + fch];
  wsB[idx] = f2bf(v * s);
  if (idx < 64) bias[idx] = beta[idx] - mean[idx] * (gamma[idx] * rsqrtf(var[idx] + 1e-3f));
}

// R5 frame (1024 blocks, wave-autonomous, no __syncthreads) with 16-deep
// batched gathers: per di, 2 batches of {read 4x(Wt,I) from LDS; issue all
// 16 corner float4 loads; then 4x bilinear+pack+ds_write}. Bf fragments are
// loaded transiently inside the MFMA phase (not live across sampling).
// Canary: WRITE_SIZE ~= 33 MB means no spills.
__global__ __launch_bounds__(256, 4) void main_kernel(
    const float* __restrict__ fmap, const float* __restrict__ y2,
    const uint4* __restrict__ wsBq, const float* __restrict__ biasg,
    float* __restrict__ out) {
  __shared__ int4   s_idx4[384];   // (lt,rt,lb,rb) base offsets
  __shared__ float4 s_wt4[384];    // (xr_x, xl_x, yt_y, yb_y)
  __shared__ uint2  fsA[4][4][64][2];  // [wave][pxblk*2+kstep][lpp][h], 16KB

  const int t    = threadIdx.x;
  const int lane = t & 63;
  const int wave = t >> 6;
  // XCD swizzle: pin one batch (fmap_b ~4.2MB ~ one XCD L2) per XCD
  const int b  = blockIdx.x & 7;
  const int oi = blockIdx.x >> 3;
  const float* fmapb = fmap + (size_t)b * (128 * 128 * 64);

  // ---- Phase 0 (wave-local): coords/weights for this wave's 32 px x 3 di ----
  #pragma unroll
  for (int it = 0; it < 2; ++it) {
    int e = lane + 64 * it;
    if (e < 96) {
      int di  = e >> 5;
      int upl = e & 31;
      int up  = wave * 32 + upl;
      int u   = di * 128 + up;
      int j   = u / 3;
      int a   = u - j * 3;
      const float4* yp = reinterpret_cast<const float4*>(
          y2 + ((size_t)(b * 128 + oi) * 128 + j) * 8);
      float4 xv = yp[0];
      float4 yv = yp[1];

      float hi01 = fmaxf(xv.x, xv.y), lo01 = fminf(xv.x, xv.y);
      float hi23 = fmaxf(xv.z, xv.w), lo23 = fminf(xv.z, xv.w);
      float top1 = fmaxf(hi01, hi23);
      float top2 = fmaxf(fminf(hi01, hi23), (hi01 >= hi23) ? lo01 : lo23);
      float w = fminf(fmaxf(top1, 1.f), 127.f) + fminf(fmaxf(top2, 1.f), 127.f);

      hi01 = fmaxf(yv.x, yv.y); lo01 = fminf(yv.x, yv.y);
      hi23 = fmaxf(yv.z, yv.w); lo23 = fminf(yv.z, yv.w);
      top1 = fmaxf(hi01, hi23);
      top2 = fmaxf(fminf(hi01, hi23), (hi01 >= hi23) ? lo01 : lo23);
      float h = fminf(fmaxf(top1, 1.f), 127.f) + fminf(fmaxf(top2, 1.f), 127.f);

      float x, yy;
      if (a == 0)      { x = ((float)j - 1.0f) - w / 3.0f;  yy = ((float)oi - 1.0f) - h / 3.0f; }
      else if (a == 1) { x = (float)j + w * 1e-10f;         yy = (float)oi + h * 1e-10f; }
      else             { x = ((float)j + 1.0f) + w / 3.0f;  yy = ((float)oi + 1.0f) + h / 3.0f; }

      float xl = fminf(fmaxf(floorf(x), 0.f), 127.f);
      float xr = fminf(fmaxf(ceilf(x),  0.f), 127.f);
      float yt = fminf(fmaxf(floorf(yy), 0.f), 127.f);
      float yb = fminf(fmaxf(ceilf(yy),  0.f), 127.f);
      int ixl = (int)xl, ixr = (int)xr, iyt = (int)yt, iyb = (int)yb;
      s_idx4[u] = make_int4((iyt * 128 + ixl) * 64, (iyt * 128 + ixr) * 64,
                            (iyb * 128 + ixl) * 64, (iyb * 128 + ixr) * 64);
      s_wt4[u]  = make_float4(xr - x, x - xl, yy - yt, yb - yy);
    }
  }
  __builtin_amdgcn_wave_barrier();

  const int px15 = lane & 15;
  const int cg   = lane & 15;          // channel quad
  const int g    = cg & 3;
  const int hh   = (cg >> 2) & 1;
  const int ksS  = cg >> 3;
  const int upg  = lane >> 4;          // pixel sub-index per iteration
  const int lsr  = lane ^ (2 * (lane >> 4));  // read-side swizzle
  const int c0   = cg * 4;

  f32x4 acc[2][4];
  #pragma unroll
  for (int j = 0; j < 4; ++j) {
    float bv = biasg[j * 16 + px15];
    acc[0][j] = (f32x4){bv, bv, bv, bv};
    acc[1][j] = (f32x4){bv, bv, bv, bv};
  }

  for (int di = 0; di < 3; ++di) {
    // ---- Sampling: 2 batches x {4 LDS reads, 16 gathers, 4 packs} ----
    #pragma unroll
    for (int bb = 0; bb < 2; ++bb) {
      float4 Wt[4];
      int4   I[4];
      #pragma unroll
      for (int k = 0; k < 4; ++k) {
        int u = di * 128 + wave * 32 + bb * 16 + k * 4 + upg;
        Wt[k] = s_wt4[u];
        I[k]  = s_idx4[u];
      }
      float4 Lt[4], Rt[4], Lb[4], Rb[4];
      #pragma unroll
      for (int k = 0; k < 4; ++k) {
        Lt[k] = Rt[k] = Lb[k] = Rb[k] = make_float4(0.f, 0.f, 0.f, 0.f);
        bool need = ((Wt[k].x != 0.f) || (Wt[k].y != 0.f)) &&
                    ((Wt[k].w != 0.f) || (Wt[k].z != 0.f));
        if (need) {
          Lt[k] = *reinterpret_cast<const float4*>(fmapb + I[k].x + c0);
          Rt[k] = *reinterpret_cast<const float4*>(fmapb + I[k].y + c0);
          Lb[k] = *reinterpret_cast<const float4*>(fmapb + I[k].z + c0);
          Rb[k] = *reinterpret_cast<const float4*>(fmapb + I[k].w + c0);
        }
      }
      #pragma unroll
      for (int k = 0; k < 4; ++k) {
        // branch-free: if weights or corners are zero, result is zero
        float xr_x = Wt[k].x, xl_x = Wt[k].y, yt_y = Wt[k].z, yb_y = Wt[k].w;
        float v0 = (xr_x * Lt[k].x + xl_x * Lb[k].x) * yb_y + (xr_x * Rt[k].x + xl_x * Rb[k].x) * yt_y;
        float v1 = (xr_x * Lt[k].y + xl_x * Lb[k].y) * yb_y + (xr_x * Rt[k].y + xl_x * Rb[k].y) * yt_y;
        float v2 = (xr_x * Lt[k].z + xl_x * Lb[k].z) * yb_y + (xr_x * Rt[k].z + xl_x * Rb[k].z) * yt_y;
        float v3 = (xr_x * Lt[k].w + xl_x * Lb[k].w) * yb_y + (xr_x * Rt[k].w + xl_x * Rb[k].w) * yt_y;
        uint2 q;
        q.x = (unsigned)f2bf(v0) | ((unsigned)f2bf(v1) << 16);
        q.y = (unsigned)f2bf(v2) | ((unsigned)f2bf(v3) << 16);
        int pxl = k * 4 + upg;                       // upl & 15
        int lpp = (pxl | (g << 4)) ^ (g << 1);       // bank swizzle
        fsA[wave][bb * 2 + ksS][lpp][hh] = q;
      }
    }
    __builtin_amdgcn_wave_barrier();

    // ---- MFMA phase: transient Bf load (L2-resident 24KB), then 16 MFMA ----
    bf16x8 Bf[8];
    #pragma unroll
    for (int jk = 0; jk < 8; ++jk)
      Bf[jk] = __builtin_bit_cast(bf16x8, wsBq[(di * 8 + jk) * 64 + lane]);
    #pragma unroll
    for (int ks = 0; ks < 2; ++ks) {
      #pragma unroll
      for (int p = 0; p < 2; ++p) {
        bf16x8 a = __builtin_bit_cast(bf16x8,
            *reinterpret_cast<const uint4*>(&fsA[wave][p * 2 + ks][lsr][0]));
        #pragma unroll
        for (int j = 0; j < 4; ++j)
          acc[p][j] = __builtin_amdgcn_mfma_f32_16x16x32_bf16(a, Bf[j * 2 + ks],
                                                              acc[p][j], 0, 0, 0);
      }
    }
    __builtin_amdgcn_wave_barrier();
  }

  // ---- Epilogue: ReLU (bias pre-folded); C/D: col=lane&15, row=(lane>>4)*4+reg ----
  float* outb = out + ((size_t)(b * 128 + oi) * 128) * 64;
  #pragma unroll
  for (int p = 0; p < 2; ++p) {
    int pxB = (wave * 2 + p) * 16 + (lane >> 4) * 4;
    #pragma unroll
    for (int j = 0; j < 4; ++j) {
      int fch = j * 16 + px15;
      #pragma unroll
      for (int reg = 0; reg < 4; ++reg) {
        outb[(size_t)(pxB + reg) * 64 + fch] = fmaxf(acc[p][j][reg], 0.f);
      }
    }
  }
}

extern "C" void kernel_launch(void* const* d_in, const int* in_sizes, int n_in,
                              void* d_out, int out_size, void* d_ws, size_t ws_size,
                              hipStream_t stream) {
  const float* fmap   = (const float*)d_in[0];
  const float* y2     = (const float*)d_in[1];
  const float* conv_w = (const float*)d_in[2];
  const float* gamma  = (const float*)d_in[3];
  const float* beta   = (const float*)d_in[4];
  const float* mean   = (const float*)d_in[5];
  const float* var    = (const float*)d_in[6];
  float* outp = (float*)d_out;

  unsigned short* wsB = (unsigned short*)d_ws;
  float* bias = (float*)((char*)d_ws + 24576);

  prep_kernel<<<48, 256, 0, stream>>>(conv_w, gamma, beta, mean, var, wsB, bias);
  main_kernel<<<1024, 256, 0, stream>>>(fmap, y2, (const uint4*)d_ws, bias, outp);
}